// Round 5
// baseline (974.490 us; speedup 1.0000x reference)
//
#include <hip/hip_runtime.h>

#define NPER 4096
#define MPER 1024
#define KNB 64
#define NB 4

typedef __attribute__((ext_vector_type(8))) short short8_t;
typedef __attribute__((ext_vector_type(4))) float f32x4;

__device__ __forceinline__ unsigned short f2bf(float f) {
  union { float f; unsigned u; } v; v.f = f;
  unsigned r = v.u + 0x7fffu + ((v.u >> 16) & 1u);
  return (unsigned short)(r >> 16);
}

// one DPP max step on a packed u64 key (both halves moved with same lane perm;
// old=src so out-of-range lanes keep their value -> no-op for max)
#define DPP_KEY_STEP(ctrl)                                                            \
  {                                                                                   \
    unsigned lo = (unsigned)k, hi = (unsigned)(k >> 32);                              \
    unsigned tlo = (unsigned)__builtin_amdgcn_update_dpp((int)lo, (int)lo, ctrl, 0xF, 0xF, false); \
    unsigned thi = (unsigned)__builtin_amdgcn_update_dpp((int)hi, (int)hi, ctrl, 0xF, 0xF, false); \
    unsigned long long tk = ((unsigned long long)thi << 32) | tlo;                    \
    if (tk > k) k = tk;                                                               \
  }

#define U64MAX(a, b) (((a) > (b)) ? (a) : (b))

// ------- FPS: 512 thr/cloud (2 waves/SIMD for latency hiding), u64 DPP argmax -------
__global__ __launch_bounds__(512) void fps_kernel(const float* __restrict__ pos,
                                                  int* __restrict__ idxout) {
  __shared__ float4 p4[NPER];                              // 64 KiB q-lookup
  __shared__ alignas(16) unsigned long long candk[2][8];   // double-buffered wave keys
  __shared__ int s_idx[MPER];                              // staged output
  const int b = blockIdx.x, t = threadIdx.x;
  const int wid = t >> 6, lane = t & 63;
  const int base = b * NPER;

  for (int i = t; i < NPER; i += 512) {
    p4[i] = make_float4(pos[(size_t)(base + i) * 3 + 0],
                        pos[(size_t)(base + i) * 3 + 1],
                        pos[(size_t)(base + i) * 3 + 2], 0.f);
  }
  __syncthreads();

  float px[8], py[8], pz[8], mind[8];
  const int i0 = t * 8;
#pragma unroll
  for (int j = 0; j < 8; ++j) {
    float4 p = p4[i0 + j];
    px[j] = p.x; py[j] = p.y; pz[j] = p.z;
    mind[j] = __builtin_inff();
  }

  int last = 0;
  for (int it = 0; it < MPER; ++it) {
    if (t == 0) s_idx[it] = last;
    if (it == MPER - 1) break;            // uniform: candidate #1024 never used
    const float4 q = p4[last];
    float bv = -1.0f; int bj = 0;
#pragma unroll
    for (int j = 0; j < 8; ++j) {
      // match JAX: (p-q)^2 summed left-to-right, NO fma contraction
      float dx = __fsub_rn(px[j], q.x);
      float dy = __fsub_rn(py[j], q.y);
      float dz = __fsub_rn(pz[j], q.z);
      float d = __fadd_rn(__fadd_rn(__fmul_rn(dx, dx), __fmul_rn(dy, dy)), __fmul_rn(dz, dz));
      float mm = fminf(mind[j], d);
      mind[j] = mm;
      if (mm > bv) { bv = mm; bj = j; }   // ascending j + strict > = first index; j inline const
    }
    const int bi = i0 + bj;
    // packed monotone key: mind >= 0 so float bits order-monotone; ties -> smaller idx
    union { float f; unsigned u; } fu; fu.f = bv;
    unsigned long long k = ((unsigned long long)fu.u << 32) | (0xFFFFFFFFu - (unsigned)bi);
    DPP_KEY_STEP(0x128)  // row_ror:8
    DPP_KEY_STEP(0x124)  // row_ror:4
    DPP_KEY_STEP(0x122)  // row_ror:2
    DPP_KEY_STEP(0x121)  // row_ror:1
    DPP_KEY_STEP(0x142)  // row_bcast15
    DPP_KEY_STEP(0x143)  // row_bcast31  -> lane 63 holds wave max
    if (lane == 63) candk[it & 1][wid] = k;
    __syncthreads();     // lgkm-only: no vmem ops in flight inside the loop
    // batched read of all 8 wave keys (4 x ds_read_b128), 7-node max tree
    const ulonglong2* ck = (const ulonglong2*)&candk[it & 1][0];
    ulonglong2 c0 = ck[0], c1 = ck[1], c2 = ck[2], c3 = ck[3];
    unsigned long long m0 = U64MAX(c0.x, c0.y);
    unsigned long long m1 = U64MAX(c1.x, c1.y);
    unsigned long long m2 = U64MAX(c2.x, c2.y);
    unsigned long long m3 = U64MAX(c3.x, c3.y);
    unsigned long long ma = U64MAX(m0, m1);
    unsigned long long mb = U64MAX(m2, m3);
    unsigned long long mg = U64MAX(ma, mb);
    last = (int)(0xFFFFFFFFu - (unsigned)mg);
    // no 2nd barrier: candk double-buffered on it&1
  }
  __syncthreads();
  for (int i = t; i < MPER; i += 512) idxout[b * MPER + i] = s_idx[i];
}

// ---------------- Ball query: radius filter + partial sort ----------------
#define CAP 1024
__global__ __launch_bounds__(256) void ballq_kernel(const float* __restrict__ pos,
                                                    const int* __restrict__ idx,
                                                    int* __restrict__ nbr) {
  __shared__ float cd[CAP];
  __shared__ int   ci[CAP];
  __shared__ int   s_cnt;
  const int c = blockIdx.x;
  const int b = c >> 10;
  const int t = threadIdx.x;
  const int base = b * NPER;
  if (t == 0) s_cnt = 0;
  __syncthreads();
  const int qi = idx[c];
  const float qx = pos[(size_t)(base + qi) * 3 + 0];
  const float qy = pos[(size_t)(base + qi) * 3 + 1];
  const float qz = pos[(size_t)(base + qi) * 3 + 2];
  const float r2f = (float)(0.2 * 0.2);
#pragma unroll
  for (int s = 0; s < 16; ++s) {
    const int i = t + s * 256;
    float dx = __fsub_rn(qx, pos[(size_t)(base + i) * 3 + 0]);
    float dy = __fsub_rn(qy, pos[(size_t)(base + i) * 3 + 1]);
    float dz = __fsub_rn(qz, pos[(size_t)(base + i) * 3 + 2]);
    float d = __fadd_rn(__fadd_rn(__fmul_rn(dx, dx), __fmul_rn(dy, dy)), __fmul_rn(dz, dz));
    if (d <= r2f) {
      int p = atomicAdd(&s_cnt, 1);
      if (p < CAP) { cd[p] = d; ci[p] = i; }
    }
  }
  __syncthreads();
  int n = s_cnt; if (n > CAP) n = CAP;
  if (n > KNB) {
    int P = 64; while (P < n) P <<= 1;
    for (int i = n + t; i < P; i += 256) { cd[i] = __builtin_inff(); ci[i] = 0x7fffffff; }
    __syncthreads();
    for (int k2 = 2; k2 <= P; k2 <<= 1) {
      for (int j = k2 >> 1; j > 0; j >>= 1) {
        for (int i = t; i < P; i += 256) {
          const int ixj = i ^ j;
          if (ixj > i) {
            const bool up = ((i & k2) == 0);
            float a = cd[i], bb = cd[ixj];
            int ia = ci[i], ib = ci[ixj];
            const bool gt = (a > bb) || (a == bb && ia > ib);
            if (gt == up) { cd[i] = bb; cd[ixj] = a; ci[i] = ib; ci[ixj] = ia; }
          }
        }
        __syncthreads();
      }
    }
  }
  if (t < KNB) nbr[c * KNB + t] = (t < n) ? ci[t] : -1;
}

// ---------------- prep: W1/W2 -> fragment-linear bf16 tables ----------------
__global__ __launch_bounds__(256) void prep_kernel(const float* __restrict__ W1,
                                                   const float* __restrict__ W2,
                                                   unsigned short* __restrict__ w1f,
                                                   unsigned short* __restrict__ w2f) {
  const int f = blockIdx.x * 256 + threadIdx.x;
  if (f < 12288) {  // W1 frags: 8 nt * 3 kt * 64 lanes * 8 e
    const int frag = f >> 9, r = f & 511, lane = r >> 3, e = r & 7;
    const int nt = frag / 3, kt = frag % 3;
    const int n = nt * 16 + (lane & 15);
    const int k = kt * 32 + (lane >> 4) * 8 + e;
    float v = (k < 67) ? W1[k * 128 + n] : 0.f;
    w1f[f] = f2bf(v);
  } else if (f < 12288 + 32768) {  // W2 frags: 16 nt * 4 kt * 64 * 8
    const int g = f - 12288;
    const int frag = g >> 9, r = g & 511, lane = r >> 3, e = r & 7;
    const int nt = frag >> 2, kt = frag & 3;
    const int n = nt * 16 + (lane & 15);
    const int k = kt * 32 + (lane >> 4) * 8 + e;
    w2f[g] = f2bf(W2[k * 256 + n]);
  }
}

// ---------------- fused gather + MLP(bf16 MFMA) + masked max ----------------
__global__ __launch_bounds__(256) void mlp_kernel(const float* __restrict__ x,
                                                  const float* __restrict__ pos,
                                                  const int* __restrict__ idx,
                                                  const int* __restrict__ nbr,
                                                  const unsigned short* __restrict__ w1f,
                                                  const unsigned short* __restrict__ w2f,
                                                  const float* __restrict__ b1,
                                                  const float* __restrict__ b2,
                                                  float* __restrict__ out) {
  __shared__ alignas(16) unsigned short s_msg[64][104];  // [k][c], K padded to 96, stride 104
  __shared__ alignas(16) unsigned short s_h1[64][136];   // [k][d1], stride 136
  __shared__ int   s_valid[64];
  __shared__ float s_red[4][256];

  const int c = blockIdx.x;
  const int b = c >> 10;
  const int t = threadIdx.x;
  const int wave = t >> 6, lane = t & 63;
  const int base = b * NPER;

  const int qi = idx[c];
  const float q0 = pos[(size_t)(base + qi) * 3 + 0];
  const float q1 = pos[(size_t)(base + qi) * 3 + 1];
  const float q2 = pos[(size_t)(base + qi) * 3 + 2];

  // ---- gather msg = [x_j | rel | 0-pad] as bf16, wave w handles 16 neighbors
#pragma unroll 1
  for (int i = 0; i < 16; ++i) {
    const int k = wave * 16 + i;
    const int j = nbr[c * KNB + k];
    if (lane == 0) s_valid[k] = (j >= 0) ? 1 : 0;
    float f = 0.f;
    if (j >= 0) f = x[(size_t)(base + j) * 64 + lane];
    s_msg[k][lane] = f2bf(f);
    if (lane < 40) {
      float rv = 0.f;
      if (lane < 3 && j >= 0) {
        float p = pos[(size_t)(base + j) * 3 + lane];
        float qq = (lane == 0) ? q0 : ((lane == 1) ? q1 : q2);
        rv = __fsub_rn(p, qq);
      }
      s_msg[k][64 + lane] = f2bf(rv);
    }
  }
  __syncthreads();

  const int row = wave * 16 + (lane & 15);
  const int kofs = (lane >> 4) * 8;

  // ---- GEMM1: h1[64x128] = relu(msg[64x96] @ W1 + b1)
  short8_t a1[3];
#pragma unroll
  for (int kt = 0; kt < 3; ++kt)
    a1[kt] = *(const short8_t*)&s_msg[row][kt * 32 + kofs];
  f32x4 acc1[8];
#pragma unroll
  for (int nt = 0; nt < 8; ++nt) acc1[nt] = (f32x4){0.f, 0.f, 0.f, 0.f};
#pragma unroll
  for (int kt = 0; kt < 3; ++kt) {
#pragma unroll
    for (int nt = 0; nt < 8; ++nt) {
      short8_t bf = *(const short8_t*)&w1f[((nt * 3 + kt) * 64 + lane) * 8];
      acc1[nt] = __builtin_amdgcn_mfma_f32_16x16x32_bf16(a1[kt], bf, acc1[nt], 0, 0, 0);
    }
  }
#pragma unroll
  for (int nt = 0; nt < 8; ++nt) {
    const int n = nt * 16 + (lane & 15);
    const float bias = b1[n];
    f32x4 v = acc1[nt];
#pragma unroll
    for (int e = 0; e < 4; ++e) {
      const int m = wave * 16 + (lane >> 4) * 4 + e;
      float h = v[e] + bias;
      h = (h > 0.f) ? h : 0.f;
      s_h1[m][n] = f2bf(h);
    }
  }
  __syncthreads();

  // ---- GEMM2: h2[64x256] = h1[64x128] @ W2, then relu+bias, mask, max over k
  short8_t a2[4];
#pragma unroll
  for (int kt = 0; kt < 4; ++kt)
    a2[kt] = *(const short8_t*)&s_h1[row][kt * 32 + kofs];
  f32x4 acc2[16];
#pragma unroll
  for (int nt = 0; nt < 16; ++nt) acc2[nt] = (f32x4){0.f, 0.f, 0.f, 0.f};
#pragma unroll
  for (int kt = 0; kt < 4; ++kt) {
#pragma unroll
    for (int nt = 0; nt < 16; ++nt) {
      short8_t bf = *(const short8_t*)&w2f[((nt * 4 + kt) * 64 + lane) * 8];
      acc2[nt] = __builtin_amdgcn_mfma_f32_16x16x32_bf16(a2[kt], bf, acc2[nt], 0, 0, 0);
    }
  }
  const int m0 = wave * 16 + (lane >> 4) * 4;
  const int vld0 = s_valid[m0 + 0], vld1 = s_valid[m0 + 1];
  const int vld2 = s_valid[m0 + 2], vld3 = s_valid[m0 + 3];
#pragma unroll
  for (int nt = 0; nt < 16; ++nt) {
    const int n = nt * 16 + (lane & 15);
    const float bias = b2[n];
    f32x4 d = acc2[nt];
    float best = -__builtin_inff();
    {
      float h;
      h = d[0] + bias; h = (h > 0.f) ? h : 0.f; if (vld0) best = fmaxf(best, h);
      h = d[1] + bias; h = (h > 0.f) ? h : 0.f; if (vld1) best = fmaxf(best, h);
      h = d[2] + bias; h = (h > 0.f) ? h : 0.f; if (vld2) best = fmaxf(best, h);
      h = d[3] + bias; h = (h > 0.f) ? h : 0.f; if (vld3) best = fmaxf(best, h);
    }
    best = fmaxf(best, __shfl_xor(best, 16, 64));
    best = fmaxf(best, __shfl_xor(best, 32, 64));
    if ((lane >> 4) == 0) s_red[wave][n] = best;
  }
  __syncthreads();
  const float r = fmaxf(fmaxf(s_red[0][t], s_red[1][t]), fmaxf(s_red[2][t], s_red[3][t]));
  out[(size_t)c * 256 + t] = r;
}

// ---------------- tail: pos/batch/weight gathers ----------------
__global__ __launch_bounds__(256) void tail_kernel(const float* __restrict__ pos,
                                                   const float* __restrict__ weight,
                                                   const int* __restrict__ idx,
                                                   float* __restrict__ out) {
  const int t = blockIdx.x * 256 + threadIdx.x;
  if (t >= NB * MPER) return;
  const int b = t >> 10;
  const int qi = idx[t];
  const int g = b * NPER + qi;
  float* pos_out = out + 1048576;          // 4096*256
  float* batch_out = out + 1048576 + 12288;
  float* w_out = out + 1048576 + 12288 + 4096;
  pos_out[t * 3 + 0] = pos[(size_t)g * 3 + 0];
  pos_out[t * 3 + 1] = pos[(size_t)g * 3 + 1];
  pos_out[t * 3 + 2] = pos[(size_t)g * 3 + 2];
  batch_out[t] = (float)b;
  w_out[t] = weight[g];
}

extern "C" void kernel_launch(void* const* d_in, const int* in_sizes, int n_in,
                              void* d_out, int out_size, void* d_ws, size_t ws_size,
                              hipStream_t stream) {
  const float* x      = (const float*)d_in[0];
  const float* pos    = (const float*)d_in[1];
  // d_in[2] = batch (unused: batch = global_index / NPER by construction)
  const float* weight = (const float*)d_in[3];
  const float* W1     = (const float*)d_in[4];
  const float* b1     = (const float*)d_in[5];
  const float* W2     = (const float*)d_in[6];
  const float* b2     = (const float*)d_in[7];
  float* out = (float*)d_out;

  char* ws = (char*)d_ws;
  int* idx = (int*)ws;                                        // 4096 * 4B
  int* nbr = (int*)(ws + 16384);                              // 4096*64 * 4B = 1 MiB
  unsigned short* w1f = (unsigned short*)(ws + 16384 + 1048576);           // 12288 * 2B
  unsigned short* w2f = (unsigned short*)(ws + 16384 + 1048576 + 24576);   // 32768 * 2B

  prep_kernel<<<176, 256, 0, stream>>>(W1, W2, w1f, w2f);
  fps_kernel<<<NB, 512, 0, stream>>>(pos, idx);
  ballq_kernel<<<NB * MPER, 256, 0, stream>>>(pos, idx, nbr);
  mlp_kernel<<<NB * MPER, 256, 0, stream>>>(x, pos, idx, nbr, w1f, w2f, b1, b2, out);
  tail_kernel<<<16, 256, 0, stream>>>(pos, weight, idx, out);
}

// Round 6
// 782.807 us; speedup vs baseline: 1.2449x; 1.2449x over previous
//
#include <hip/hip_runtime.h>

#define NPER 4096
#define MPER 1024
#define KNB 64
#define NB 4

typedef __attribute__((ext_vector_type(8))) short short8_t;
typedef __attribute__((ext_vector_type(4))) float f32x4;
typedef __attribute__((ext_vector_type(2))) float f32x2;

__device__ __forceinline__ unsigned short f2bf(float f) {
  union { float f; unsigned u; } v; v.f = f;
  unsigned r = v.u + 0x7fffu + ((v.u >> 16) & 1u);
  return (unsigned short)(r >> 16);
}

// packed fp32 (VOP3P) helpers: 2 points per instruction, IEEE rn, no contraction
__device__ __forceinline__ f32x2 pk_add(f32x2 a, f32x2 b) {
  f32x2 d; asm("v_pk_add_f32 %0, %1, %2" : "=v"(d) : "v"(a), "v"(b)); return d;
}
__device__ __forceinline__ f32x2 pk_mul(f32x2 a, f32x2 b) {
  f32x2 d; asm("v_pk_mul_f32 %0, %1, %2" : "=v"(d) : "v"(a), "v"(b)); return d;
}

// one DPP max step on a packed u64 key (old=src so inactive lanes no-op for max)
#define DPP_KEY_STEP(ctrl)                                                            \
  {                                                                                   \
    unsigned lo = (unsigned)k, hi = (unsigned)(k >> 32);                              \
    unsigned tlo = (unsigned)__builtin_amdgcn_update_dpp((int)lo, (int)lo, ctrl, 0xF, 0xF, false); \
    unsigned thi = (unsigned)__builtin_amdgcn_update_dpp((int)hi, (int)hi, ctrl, 0xF, 0xF, false); \
    unsigned long long tk = ((unsigned long long)thi << 32) | tlo;                    \
    if (tk > k) k = tk;                                                               \
  }

#define U64MAX(a, b) (((a) > (b)) ? (a) : (b))

// ------- FPS: 256 thr/cloud (1 wave/SIMD), packed-f32 dist, u64 DPP argmax -------
__global__ __launch_bounds__(256) void fps_kernel(const float* __restrict__ pos,
                                                  int* __restrict__ idxout) {
  __shared__ float4 p4[NPER];                              // 64 KiB q-lookup
  __shared__ alignas(16) unsigned long long candk[2][4];   // double-buffered wave keys
  __shared__ int s_idx[MPER];                              // staged output
  const int b = blockIdx.x, t = threadIdx.x;
  const int wid = t >> 6, lane = t & 63;
  const int base = b * NPER;

  for (int i = t; i < NPER; i += 256) {
    p4[i] = make_float4(pos[(size_t)(base + i) * 3 + 0],
                        pos[(size_t)(base + i) * 3 + 1],
                        pos[(size_t)(base + i) * 3 + 2], 0.f);
  }
  __syncthreads();

  // 16 points/thread as 8 packed pairs per component
  f32x2 pxp[8], pyp[8], pzp[8];
  float mnd[16];
  const int i0 = t * 16;
#pragma unroll
  for (int p = 0; p < 8; ++p) {
    float4 a = p4[i0 + 2 * p];
    float4 c = p4[i0 + 2 * p + 1];
    pxp[p] = (f32x2){a.x, c.x};
    pyp[p] = (f32x2){a.y, c.y};
    pzp[p] = (f32x2){a.z, c.z};
  }
#pragma unroll
  for (int j = 0; j < 16; ++j) mnd[j] = __builtin_inff();

  int last = 0;
  for (int it = 0; it < MPER; ++it) {
    if (t == 0) s_idx[it] = last;
    if (it == MPER - 1) break;            // candidate #1024 never used
    const float4 q = p4[last];
    // p + (-q) is bit-identical to p - q (IEEE); negation is exact
    const f32x2 nqx = (f32x2){-q.x, -q.x};
    const f32x2 nqy = (f32x2){-q.y, -q.y};
    const f32x2 nqz = (f32x2){-q.z, -q.z};
    float bv = -1.0f; int bj = 0;
#pragma unroll
    for (int p = 0; p < 8; ++p) {
      f32x2 dx = pk_add(pxp[p], nqx);
      f32x2 dy = pk_add(pyp[p], nqy);
      f32x2 dz = pk_add(pzp[p], nqz);
      // (dx*dx + dy*dy) + dz*dz, left-to-right, no fma (asm is opaque to fusion)
      f32x2 s = pk_add(pk_add(pk_mul(dx, dx), pk_mul(dy, dy)), pk_mul(dz, dz));
      float m0 = fminf(mnd[2 * p], s.x);     mnd[2 * p] = m0;
      if (m0 > bv) { bv = m0; bj = 2 * p; }      // ascending idx + strict > = first max
      float m1 = fminf(mnd[2 * p + 1], s.y); mnd[2 * p + 1] = m1;
      if (m1 > bv) { bv = m1; bj = 2 * p + 1; }
    }
    const int bi = i0 + bj;
    // packed monotone key: mnd >= 0 so float bits order-monotone; ties -> smaller idx
    union { float f; unsigned u; } fu; fu.f = bv;
    unsigned long long k = ((unsigned long long)fu.u << 32) | (0xFFFFFFFFu - (unsigned)bi);
    DPP_KEY_STEP(0x128)  // row_ror:8
    DPP_KEY_STEP(0x124)  // row_ror:4
    DPP_KEY_STEP(0x122)  // row_ror:2
    DPP_KEY_STEP(0x121)  // row_ror:1
    DPP_KEY_STEP(0x142)  // row_bcast15
    DPP_KEY_STEP(0x143)  // row_bcast31  -> lane 63 holds wave max
    if (lane == 63) candk[it & 1][wid] = k;
    __syncthreads();     // lgkm-only: no vmem ops in flight inside the loop
    const ulonglong2* ck = (const ulonglong2*)&candk[it & 1][0];
    ulonglong2 c0 = ck[0], c1 = ck[1];
    unsigned long long m0 = U64MAX(c0.x, c0.y);
    unsigned long long m1 = U64MAX(c1.x, c1.y);
    unsigned long long mg = U64MAX(m0, m1);
    last = (int)(0xFFFFFFFFu - (unsigned)mg);
    // no 2nd barrier: candk double-buffered on it&1
  }
  __syncthreads();
  for (int i = t; i < MPER; i += 256) idxout[b * MPER + i] = s_idx[i];
}

// ---------------- Ball query: radius filter + partial sort ----------------
#define CAP 1024
__global__ __launch_bounds__(256) void ballq_kernel(const float* __restrict__ pos,
                                                    const int* __restrict__ idx,
                                                    int* __restrict__ nbr) {
  __shared__ float cd[CAP];
  __shared__ int   ci[CAP];
  __shared__ int   s_cnt;
  const int c = blockIdx.x;
  const int b = c >> 10;
  const int t = threadIdx.x;
  const int base = b * NPER;
  if (t == 0) s_cnt = 0;
  __syncthreads();
  const int qi = idx[c];
  const float qx = pos[(size_t)(base + qi) * 3 + 0];
  const float qy = pos[(size_t)(base + qi) * 3 + 1];
  const float qz = pos[(size_t)(base + qi) * 3 + 2];
  const float r2f = (float)(0.2 * 0.2);
#pragma unroll
  for (int s = 0; s < 16; ++s) {
    const int i = t + s * 256;
    float dx = __fsub_rn(qx, pos[(size_t)(base + i) * 3 + 0]);
    float dy = __fsub_rn(qy, pos[(size_t)(base + i) * 3 + 1]);
    float dz = __fsub_rn(qz, pos[(size_t)(base + i) * 3 + 2]);
    float d = __fadd_rn(__fadd_rn(__fmul_rn(dx, dx), __fmul_rn(dy, dy)), __fmul_rn(dz, dz));
    if (d <= r2f) {
      int p = atomicAdd(&s_cnt, 1);
      if (p < CAP) { cd[p] = d; ci[p] = i; }
    }
  }
  __syncthreads();
  int n = s_cnt; if (n > CAP) n = CAP;
  if (n > KNB) {
    int P = 64; while (P < n) P <<= 1;
    for (int i = n + t; i < P; i += 256) { cd[i] = __builtin_inff(); ci[i] = 0x7fffffff; }
    __syncthreads();
    for (int k2 = 2; k2 <= P; k2 <<= 1) {
      for (int j = k2 >> 1; j > 0; j >>= 1) {
        for (int i = t; i < P; i += 256) {
          const int ixj = i ^ j;
          if (ixj > i) {
            const bool up = ((i & k2) == 0);
            float a = cd[i], bb = cd[ixj];
            int ia = ci[i], ib = ci[ixj];
            const bool gt = (a > bb) || (a == bb && ia > ib);
            if (gt == up) { cd[i] = bb; cd[ixj] = a; ci[i] = ib; ci[ixj] = ia; }
          }
        }
        __syncthreads();
      }
    }
  }
  if (t < KNB) nbr[c * KNB + t] = (t < n) ? ci[t] : -1;
}

// ---------------- prep: W1/W2 -> fragment-linear bf16 tables ----------------
__global__ __launch_bounds__(256) void prep_kernel(const float* __restrict__ W1,
                                                   const float* __restrict__ W2,
                                                   unsigned short* __restrict__ w1f,
                                                   unsigned short* __restrict__ w2f) {
  const int f = blockIdx.x * 256 + threadIdx.x;
  if (f < 12288) {  // W1 frags: 8 nt * 3 kt * 64 lanes * 8 e
    const int frag = f >> 9, r = f & 511, lane = r >> 3, e = r & 7;
    const int nt = frag / 3, kt = frag % 3;
    const int n = nt * 16 + (lane & 15);
    const int k = kt * 32 + (lane >> 4) * 8 + e;
    float v = (k < 67) ? W1[k * 128 + n] : 0.f;
    w1f[f] = f2bf(v);
  } else if (f < 12288 + 32768) {  // W2 frags: 16 nt * 4 kt * 64 * 8
    const int g = f - 12288;
    const int frag = g >> 9, r = g & 511, lane = r >> 3, e = r & 7;
    const int nt = frag >> 2, kt = frag & 3;
    const int n = nt * 16 + (lane & 15);
    const int k = kt * 32 + (lane >> 4) * 8 + e;
    w2f[g] = f2bf(W2[k * 256 + n]);
  }
}

// ---------------- fused gather + MLP(bf16 MFMA) + masked max ----------------
__global__ __launch_bounds__(256) void mlp_kernel(const float* __restrict__ x,
                                                  const float* __restrict__ pos,
                                                  const int* __restrict__ idx,
                                                  const int* __restrict__ nbr,
                                                  const unsigned short* __restrict__ w1f,
                                                  const unsigned short* __restrict__ w2f,
                                                  const float* __restrict__ b1,
                                                  const float* __restrict__ b2,
                                                  float* __restrict__ out) {
  __shared__ alignas(16) unsigned short s_msg[64][104];  // [k][c], K padded to 96, stride 104
  __shared__ alignas(16) unsigned short s_h1[64][136];   // [k][d1], stride 136
  __shared__ int   s_valid[64];
  __shared__ float s_red[4][256];

  const int c = blockIdx.x;
  const int b = c >> 10;
  const int t = threadIdx.x;
  const int wave = t >> 6, lane = t & 63;
  const int base = b * NPER;

  const int qi = idx[c];
  const float q0 = pos[(size_t)(base + qi) * 3 + 0];
  const float q1 = pos[(size_t)(base + qi) * 3 + 1];
  const float q2 = pos[(size_t)(base + qi) * 3 + 2];

  // whole nbr row loaded once (lane l -> neighbor for k=l), broadcast via shfl
  const int nbrv = nbr[c * KNB + lane];
  s_valid[lane] = (nbrv >= 0) ? 1 : 0;   // waves write identical values - benign

  // ---- gather msg = [x_j | rel | 0-pad] as bf16, wave w handles 16 neighbors
#pragma unroll 4
  for (int i = 0; i < 16; ++i) {
    const int k = wave * 16 + i;
    const int j = __shfl(nbrv, k, 64);
    float f = 0.f;
    if (j >= 0) f = x[(size_t)(base + j) * 64 + lane];
    s_msg[k][lane] = f2bf(f);
    if (lane < 40) {
      float rv = 0.f;
      if (lane < 3 && j >= 0) {
        float p = pos[(size_t)(base + j) * 3 + lane];
        float qq = (lane == 0) ? q0 : ((lane == 1) ? q1 : q2);
        rv = __fsub_rn(p, qq);
      }
      s_msg[k][64 + lane] = f2bf(rv);
    }
  }
  __syncthreads();

  const int row = wave * 16 + (lane & 15);
  const int kofs = (lane >> 4) * 8;

  // ---- GEMM1: h1[64x128] = relu(msg[64x96] @ W1 + b1)
  short8_t a1[3];
#pragma unroll
  for (int kt = 0; kt < 3; ++kt)
    a1[kt] = *(const short8_t*)&s_msg[row][kt * 32 + kofs];
  f32x4 acc1[8];
#pragma unroll
  for (int nt = 0; nt < 8; ++nt) acc1[nt] = (f32x4){0.f, 0.f, 0.f, 0.f};
#pragma unroll
  for (int kt = 0; kt < 3; ++kt) {
#pragma unroll
    for (int nt = 0; nt < 8; ++nt) {
      short8_t bf = *(const short8_t*)&w1f[((nt * 3 + kt) * 64 + lane) * 8];
      acc1[nt] = __builtin_amdgcn_mfma_f32_16x16x32_bf16(a1[kt], bf, acc1[nt], 0, 0, 0);
    }
  }
#pragma unroll
  for (int nt = 0; nt < 8; ++nt) {
    const int n = nt * 16 + (lane & 15);
    const float bias = b1[n];
    f32x4 v = acc1[nt];
#pragma unroll
    for (int e = 0; e < 4; ++e) {
      const int m = wave * 16 + (lane >> 4) * 4 + e;
      float h = v[e] + bias;
      h = (h > 0.f) ? h : 0.f;
      s_h1[m][n] = f2bf(h);
    }
  }
  __syncthreads();

  // ---- GEMM2: h2[64x256] = h1[64x128] @ W2, then relu+bias, mask, max over k
  short8_t a2[4];
#pragma unroll
  for (int kt = 0; kt < 4; ++kt)
    a2[kt] = *(const short8_t*)&s_h1[row][kt * 32 + kofs];
  f32x4 acc2[16];
#pragma unroll
  for (int nt = 0; nt < 16; ++nt) acc2[nt] = (f32x4){0.f, 0.f, 0.f, 0.f};
#pragma unroll
  for (int kt = 0; kt < 4; ++kt) {
#pragma unroll
    for (int nt = 0; nt < 16; ++nt) {
      short8_t bf = *(const short8_t*)&w2f[((nt * 4 + kt) * 64 + lane) * 8];
      acc2[nt] = __builtin_amdgcn_mfma_f32_16x16x32_bf16(a2[kt], bf, acc2[nt], 0, 0, 0);
    }
  }
  const int m0 = wave * 16 + (lane >> 4) * 4;
  const int vld0 = s_valid[m0 + 0], vld1 = s_valid[m0 + 1];
  const int vld2 = s_valid[m0 + 2], vld3 = s_valid[m0 + 3];
#pragma unroll
  for (int nt = 0; nt < 16; ++nt) {
    const int n = nt * 16 + (lane & 15);
    const float bias = b2[n];
    f32x4 d = acc2[nt];
    float best = -__builtin_inff();
    {
      float h;
      h = d[0] + bias; h = (h > 0.f) ? h : 0.f; if (vld0) best = fmaxf(best, h);
      h = d[1] + bias; h = (h > 0.f) ? h : 0.f; if (vld1) best = fmaxf(best, h);
      h = d[2] + bias; h = (h > 0.f) ? h : 0.f; if (vld2) best = fmaxf(best, h);
      h = d[3] + bias; h = (h > 0.f) ? h : 0.f; if (vld3) best = fmaxf(best, h);
    }
    best = fmaxf(best, __shfl_xor(best, 16, 64));
    best = fmaxf(best, __shfl_xor(best, 32, 64));
    if ((lane >> 4) == 0) s_red[wave][n] = best;
  }
  __syncthreads();
  const float r = fmaxf(fmaxf(s_red[0][t], s_red[1][t]), fmaxf(s_red[2][t], s_red[3][t]));
  out[(size_t)c * 256 + t] = r;
}

// ---------------- tail: pos/batch/weight gathers ----------------
__global__ __launch_bounds__(256) void tail_kernel(const float* __restrict__ pos,
                                                   const float* __restrict__ weight,
                                                   const int* __restrict__ idx,
                                                   float* __restrict__ out) {
  const int t = blockIdx.x * 256 + threadIdx.x;
  if (t >= NB * MPER) return;
  const int b = t >> 10;
  const int qi = idx[t];
  const int g = b * NPER + qi;
  float* pos_out = out + 1048576;          // 4096*256
  float* batch_out = out + 1048576 + 12288;
  float* w_out = out + 1048576 + 12288 + 4096;
  pos_out[t * 3 + 0] = pos[(size_t)g * 3 + 0];
  pos_out[t * 3 + 1] = pos[(size_t)g * 3 + 1];
  pos_out[t * 3 + 2] = pos[(size_t)g * 3 + 2];
  batch_out[t] = (float)b;
  w_out[t] = weight[g];
}

extern "C" void kernel_launch(void* const* d_in, const int* in_sizes, int n_in,
                              void* d_out, int out_size, void* d_ws, size_t ws_size,
                              hipStream_t stream) {
  const float* x      = (const float*)d_in[0];
  const float* pos    = (const float*)d_in[1];
  // d_in[2] = batch (unused: batch = global_index / NPER by construction)
  const float* weight = (const float*)d_in[3];
  const float* W1     = (const float*)d_in[4];
  const float* b1     = (const float*)d_in[5];
  const float* W2     = (const float*)d_in[6];
  const float* b2     = (const float*)d_in[7];
  float* out = (float*)d_out;

  char* ws = (char*)d_ws;
  int* idx = (int*)ws;                                        // 4096 * 4B
  int* nbr = (int*)(ws + 16384);                              // 4096*64 * 4B = 1 MiB
  unsigned short* w1f = (unsigned short*)(ws + 16384 + 1048576);           // 12288 * 2B
  unsigned short* w2f = (unsigned short*)(ws + 16384 + 1048576 + 24576);   // 32768 * 2B

  prep_kernel<<<176, 256, 0, stream>>>(W1, W2, w1f, w2f);
  fps_kernel<<<NB, 256, 0, stream>>>(pos, idx);
  ballq_kernel<<<NB * MPER, 256, 0, stream>>>(pos, idx, nbr);
  mlp_kernel<<<NB * MPER, 256, 0, stream>>>(x, pos, idx, nbr, w1f, w2f, b1, b2, out);
  tail_kernel<<<16, 256, 0, stream>>>(pos, weight, idx, out);
}